// Round 2
// baseline (219.927 us; speedup 1.0000x reference)
//
#include <hip/hip_runtime.h>
#include <math.h>

#define BB   16
#define CC   4
#define HH   640
#define WW   640
#define HWSZ (HH*WW)        // 409600 pixels per image
#define KM   16             // labels 1..16 tracked; 0 = background (derived)
#define NSUM (KM*CC)        // 64 channel-sum slots per image
#define NACC (NSUM+KM)      // + 16 counts = 80 ws floats per image
#define SIGMA_D 3.0f

// ---------------------------------------------------------------------------
// Kernel 1: per-(image,label) channel sums + counts.
// Channel sums: 64 statically-indexed VGPR accumulators per thread,
// wave butterfly reduce, lane0 -> global atomicAdd.
// Counts: __ballot + popcount (wave-uniform, SALU side), lane0 atomicAdd.
// grid = (64, B), block = 256. ALL acc indexing is compile-time static
// (runtime indexing would spill the array to scratch -- round-1 bug).
// ---------------------------------------------------------------------------
__global__ __launch_bounds__(256, 4) void seg_kernel(
    const float* __restrict__ pred, const int* __restrict__ labels,
    float* __restrict__ ws)
{
    const int b = blockIdx.y;
    const int t = threadIdx.x;

    const int4*   lab = (const int4*)(labels + (size_t)b * HWSZ);
    const float4* p0  = (const float4*)(pred + ((size_t)b * CC + 0) * HWSZ);
    const float4* p1  = (const float4*)(pred + ((size_t)b * CC + 1) * HWSZ);
    const float4* p2  = (const float4*)(pred + ((size_t)b * CC + 2) * HWSZ);
    const float4* p3  = (const float4*)(pred + ((size_t)b * CC + 3) * HWSZ);

    const int NGROUPS = HWSZ / 4;          // 102400 float4-groups per image
    const int STRIDE  = gridDim.x * 256;

    float acc[NSUM];
    #pragma unroll
    for (int i = 0; i < NSUM; ++i) acc[i] = 0.f;
    int cnt[KM];
    #pragma unroll
    for (int i = 0; i < KM; ++i) cnt[i] = 0;

    for (int g = blockIdx.x * 256 + t; g < NGROUPS; g += STRIDE) {
        int4   L  = lab[g];
        float4 v0 = p0[g], v1 = p1[g], v2 = p2[g], v3 = p3[g];
        int   lb4[4] = {L.x, L.y, L.z, L.w};
        float a0[4]  = {v0.x, v0.y, v0.z, v0.w};
        float a1[4]  = {v1.x, v1.y, v1.z, v1.w};
        float a2[4]  = {v2.x, v2.y, v2.z, v2.w};
        float a3[4]  = {v3.x, v3.y, v3.z, v3.w};
        #pragma unroll
        for (int j = 0; j < 4; ++j) {
            int lb = lb4[j];
            #pragma unroll
            for (int k = 1; k <= KM; ++k) {
                bool hit = (lb == k);
                // wave-uniform count: ballot+popcount stays on the scalar side
                cnt[k-1] += (int)__popcll(__ballot(hit));
                float m = hit ? 1.0f : 0.0f;
                acc[(k-1)*4+0] = fmaf(m, a0[j], acc[(k-1)*4+0]);
                acc[(k-1)*4+1] = fmaf(m, a1[j], acc[(k-1)*4+1]);
                acc[(k-1)*4+2] = fmaf(m, a2[j], acc[(k-1)*4+2]);
                acc[(k-1)*4+3] = fmaf(m, a3[j], acc[(k-1)*4+3]);
            }
        }
    }

    // wave butterfly reduce of the 64 channel sums (all indices static)
    #pragma unroll
    for (int i = 0; i < NSUM; ++i) {
        float v = acc[i];
        v += __shfl_xor(v, 1);
        v += __shfl_xor(v, 2);
        v += __shfl_xor(v, 4);
        v += __shfl_xor(v, 8);
        v += __shfl_xor(v, 16);
        v += __shfl_xor(v, 32);
        acc[i] = v;
    }

    if ((t & 63) == 0) {
        float* wsb = ws + b * NACC;
        #pragma unroll
        for (int i = 0; i < NSUM; ++i) atomicAdd(&wsb[i], acc[i]);
        #pragma unroll
        for (int k = 0; k < KM; ++k) atomicAdd(&wsb[NSUM + k], (float)cnt[k]);
    }
}

// ---------------------------------------------------------------------------
// Kernel 2: tiny epilogue — N, f, sum_g, Kb, own/other/scale, scalar out.
// ---------------------------------------------------------------------------
__global__ void finalize_kernel(const float* __restrict__ ws, float* __restrict__ out)
{
    __shared__ float s_sumg[BB], s_P[BB], s_Kb[BB];
    const float F0 = logf(SIGMA_D * SIGMA_D + 1.0f);   // log(10)
    int b = threadIdx.x;
    if (b < BB) {
        const float* w = ws + b * NACC;
        float cnt_sum = 0.f, sum_g = 0.f, Kb = 0.f;
        for (int k = 1; k <= KM; ++k) {
            float s0 = w[(k-1)*4+0], s1 = w[(k-1)*4+1];
            float s2 = w[(k-1)*4+2], s3 = w[(k-1)*4+3];
            float cn = w[NSUM + (k-1)];
            float N  = sqrtf(s0*s0 + s1*s1 + s2*s2 + s3*s3);
            float r  = fmaxf(SIGMA_D - N, 0.f);
            float f  = logf(r*r + 1.0f);
            sum_g   += cn * f;
            cnt_sum += cn;
            if (cn > 0.f) Kb = (float)k;
        }
        float c0 = (float)HWSZ - cnt_sum;     // background count
        sum_g += c0 * F0;
        s_sumg[b] = sum_g;
        s_Kb[b]   = Kb;
        s_P[b]    = (Kb > 1.f) ? Kb * (Kb - 1.f) * 0.5f : 0.f;  // P_act
    }
    __syncthreads();
    if (threadIdx.x == 0) {
        double sumP = 0.0;
        for (int i = 0; i < BB; ++i) sumP += (double)s_P[i];
        double total = 0.0;
        for (int i = 0; i < BB; ++i) {
            double Kb   = (double)s_Kb[i];
            double Pact = (double)s_P[i];
            double own  = 0.0;
            if (Kb > 1.0)
                own = (Kb - 1.0) * (double)s_sumg[i]
                    + (double)HWSZ * (Pact - (Kb - 1.0)) * (double)F0;
            double other = (sumP - Pact) * (double)HWSZ * (double)F0;
            double scale = (Kb > 1.0) ? 1.0 / (Kb * (Kb - 1.0)) : Kb;
            total += scale * (own + other);
        }
        out[0] = (float)total;
    }
}

// ---------------------------------------------------------------------------
extern "C" void kernel_launch(void* const* d_in, const int* in_sizes, int n_in,
                              void* d_out, int out_size, void* d_ws, size_t ws_size,
                              hipStream_t stream)
{
    const float* pred   = (const float*)d_in[0];
    const int*   labels = (const int*)d_in[1];
    float*       out    = (float*)d_out;
    float*       ws     = (float*)d_ws;

    hipMemsetAsync(ws, 0, BB * NACC * sizeof(float), stream);

    dim3 grid(64, BB);
    seg_kernel<<<grid, 256, 0, stream>>>(pred, labels, ws);
    finalize_kernel<<<1, 64, 0, stream>>>(ws, out);
}

// Round 3
// 202.222 us; speedup vs baseline: 1.0876x; 1.0876x over previous
//
#include <hip/hip_runtime.h>
#include <math.h>

#define BB   16
#define CC   4
#define HH   640
#define WW   640
#define HWSZ (HH*WW)        // 409600 pixels per image
#define KM   16             // labels 1..16 tracked; 0 = background (derived)
#define NSUM (KM*CC)        // 64 channel-sum slots per image
#define NACC (NSUM+KM)      // + 16 counts = 80 ws floats per image
#define SIGMA_D 3.0f

#define NWAVE 4             // waves per block (256 threads)
#define SLOTS 85            // 17 labels x 5 (4 ch sums + count); label 0 = dummy
#define SLOTP 90            // padded per-wave stride

// ---------------------------------------------------------------------------
// Kernel 1: per-(image,label) channel sums + counts via per-wave-privatized
// LDS float atomics (ds_add_f32). No large per-thread register arrays ->
// nothing to spill (rounds 1-2 both died on acc[] scratch spills).
// Per pixel: 5 LDS atomics into this wave's 85-float region. Label 0 goes to
// a dummy slot (branch-free). Block epilogue sums the 4 wave regions and does
// 80 global atomicAdds into zeroed ws[b*80 + slot].
// grid = (64, B), block = 256.
// ---------------------------------------------------------------------------
__global__ __launch_bounds__(256) void seg_kernel(
    const float* __restrict__ pred, const int* __restrict__ labels,
    float* __restrict__ ws)
{
    const int b    = blockIdx.y;
    const int t    = threadIdx.x;
    const int wave = t >> 6;

    __shared__ float sacc[NWAVE * SLOTP];
    for (int i = t; i < NWAVE * SLOTP; i += 256) sacc[i] = 0.f;
    __syncthreads();

    float* my = sacc + wave * SLOTP;

    const int4*   lab = (const int4*)(labels + (size_t)b * HWSZ);
    const float4* p0  = (const float4*)(pred + ((size_t)b * CC + 0) * HWSZ);
    const float4* p1  = (const float4*)(pred + ((size_t)b * CC + 1) * HWSZ);
    const float4* p2  = (const float4*)(pred + ((size_t)b * CC + 2) * HWSZ);
    const float4* p3  = (const float4*)(pred + ((size_t)b * CC + 3) * HWSZ);

    const int NGROUPS = HWSZ / 4;          // 102400 float4-groups per image
    const int STRIDE  = gridDim.x * 256;

    for (int g = blockIdx.x * 256 + t; g < NGROUPS; g += STRIDE) {
        int4   L  = lab[g];
        float4 v0 = p0[g], v1 = p1[g], v2 = p2[g], v3 = p3[g];
        {   // pixel 0
            float* s = my + L.x * 5;
            atomicAdd(s + 0, v0.x); atomicAdd(s + 1, v1.x);
            atomicAdd(s + 2, v2.x); atomicAdd(s + 3, v3.x);
            atomicAdd(s + 4, 1.0f);
        }
        {   // pixel 1
            float* s = my + L.y * 5;
            atomicAdd(s + 0, v0.y); atomicAdd(s + 1, v1.y);
            atomicAdd(s + 2, v2.y); atomicAdd(s + 3, v3.y);
            atomicAdd(s + 4, 1.0f);
        }
        {   // pixel 2
            float* s = my + L.z * 5;
            atomicAdd(s + 0, v0.z); atomicAdd(s + 1, v1.z);
            atomicAdd(s + 2, v2.z); atomicAdd(s + 3, v3.z);
            atomicAdd(s + 4, 1.0f);
        }
        {   // pixel 3
            float* s = my + L.w * 5;
            atomicAdd(s + 0, v0.w); atomicAdd(s + 1, v1.w);
            atomicAdd(s + 2, v2.w); atomicAdd(s + 3, v3.w);
            atomicAdd(s + 4, 1.0f);
        }
    }
    __syncthreads();

    // block epilogue: fold 4 wave regions, scatter to ws (skip label-0 slots)
    if (t >= 5 && t < SLOTS) {            // slots 5..84 = labels 1..16
        float v = sacc[0 * SLOTP + t] + sacc[1 * SLOTP + t]
                + sacc[2 * SLOTP + t] + sacc[3 * SLOTP + t];
        int lb = t / 5;                   // 1..16
        int c  = t - lb * 5;              // 0..4
        int idx = (c < 4) ? ((lb - 1) * 4 + c) : (NSUM + (lb - 1));
        atomicAdd(&ws[b * NACC + idx], v);
    }
}

// ---------------------------------------------------------------------------
// Kernel 2: tiny epilogue — N, f, sum_g, Kb, own/other/scale, scalar out.
// ---------------------------------------------------------------------------
__global__ void finalize_kernel(const float* __restrict__ ws, float* __restrict__ out)
{
    __shared__ float s_sumg[BB], s_P[BB], s_Kb[BB];
    const float F0 = logf(SIGMA_D * SIGMA_D + 1.0f);   // log(10)
    int b = threadIdx.x;
    if (b < BB) {
        const float* w = ws + b * NACC;
        float cnt_sum = 0.f, sum_g = 0.f, Kb = 0.f;
        for (int k = 1; k <= KM; ++k) {
            float s0 = w[(k-1)*4+0], s1 = w[(k-1)*4+1];
            float s2 = w[(k-1)*4+2], s3 = w[(k-1)*4+3];
            float cn = w[NSUM + (k-1)];
            float N  = sqrtf(s0*s0 + s1*s1 + s2*s2 + s3*s3);
            float r  = fmaxf(SIGMA_D - N, 0.f);
            float f  = logf(r*r + 1.0f);
            sum_g   += cn * f;
            cnt_sum += cn;
            if (cn > 0.f) Kb = (float)k;
        }
        float c0 = (float)HWSZ - cnt_sum;     // background count
        sum_g += c0 * F0;
        s_sumg[b] = sum_g;
        s_Kb[b]   = Kb;
        s_P[b]    = (Kb > 1.f) ? Kb * (Kb - 1.f) * 0.5f : 0.f;  // P_act
    }
    __syncthreads();
    if (threadIdx.x == 0) {
        double sumP = 0.0;
        for (int i = 0; i < BB; ++i) sumP += (double)s_P[i];
        double total = 0.0;
        for (int i = 0; i < BB; ++i) {
            double Kb   = (double)s_Kb[i];
            double Pact = (double)s_P[i];
            double own  = 0.0;
            if (Kb > 1.0)
                own = (Kb - 1.0) * (double)s_sumg[i]
                    + (double)HWSZ * (Pact - (Kb - 1.0)) * (double)F0;
            double other = (sumP - Pact) * (double)HWSZ * (double)F0;
            double scale = (Kb > 1.0) ? 1.0 / (Kb * (Kb - 1.0)) : Kb;
            total += scale * (own + other);
        }
        out[0] = (float)total;
    }
}

// ---------------------------------------------------------------------------
extern "C" void kernel_launch(void* const* d_in, const int* in_sizes, int n_in,
                              void* d_out, int out_size, void* d_ws, size_t ws_size,
                              hipStream_t stream)
{
    const float* pred   = (const float*)d_in[0];
    const int*   labels = (const int*)d_in[1];
    float*       out    = (float*)d_out;
    float*       ws     = (float*)d_ws;

    hipMemsetAsync(ws, 0, BB * NACC * sizeof(float), stream);

    dim3 grid(64, BB);
    seg_kernel<<<grid, 256, 0, stream>>>(pred, labels, ws);
    finalize_kernel<<<1, 64, 0, stream>>>(ws, out);
}